// Round 10
// baseline (119.074 us; speedup 1.0000x reference)
//
#include <hip/hip_runtime.h>
#include <math.h>

#define N 4096
#define D 128
#define P 16
#define KK 2048                    // P*D, single f16 plane
#define NT 32
#define NBLK (NT * (NT + 1) / 2)   // 528 upper-tri blocks
#define LCAP 2048                  // per-block LDS worklist (8 KB)
#define CAP (1u << 20)             // global worklist capacity (4 MB)
#define WIN 1.5e-3f                // > 1.1e-3 rigorous scaled-f16 bound
#define ZSCALE 256.0f              // 2^8, exact
#define OSCALE (1.0f / 16777216.0f * 16.0f)  // 0.0625 * 2^-16 = 2^-20, exact

typedef _Float16 half_t;
typedef __attribute__((ext_vector_type(8))) _Float16 f16x8;
typedef __attribute__((ext_vector_type(4))) float f32x4;
typedef __attribute__((address_space(1))) const unsigned int* gptr_t;
typedef __attribute__((address_space(3))) unsigned int* lptr_t;

// ---------------------------------------------------------------------------
// K1: fused norms (f64, cross-lane reduce) + scaled f16 pack + counter init.
// ---------------------------------------------------------------------------
__global__ __launch_bounds__(256) void k_pack(const float* __restrict__ c,
                                              const float* __restrict__ w,
                                              double* __restrict__ rnorm,
                                              half_t* __restrict__ zb,
                                              unsigned* gcnt, unsigned* govf,
                                              int do_init) {
    int n = blockIdx.x, tid = threadIdx.x;
    if (do_init && n == 0 && tid == 0) { *gcnt = 0; *govf = 0; }
    int p = tid >> 4, d0 = (tid & 15) * 8;
    const float* cc = c + (size_t)n * D + d0;
    const float* ww = w + (size_t)p * D + d0;
    float cv[8], wv[8];
    *(float4*)&cv[0] = *(const float4*)&cc[0];
    *(float4*)&cv[4] = *(const float4*)&cc[4];
    *(float4*)&wv[0] = *(const float4*)&ww[0];
    *(float4*)&wv[4] = *(const float4*)&ww[4];
    double s = 0.0;
#pragma unroll
    for (int i = 0; i < 8; ++i) {
        double v = (double)cv[i] * (double)wv[i];
        s += v * v;
    }
#pragma unroll
    for (int o = 1; o < 16; o <<= 1) s += __shfl_xor(s, o, 64);
    double rn = 1.0 / fmax(sqrt(s), 1e-12);
    if ((tid & 15) == 0) rnorm[p * N + n] = rn;
    float rnf = (float)rn;
    f16x8 o8;
#pragma unroll
    for (int i = 0; i < 8; ++i) o8[i] = (half_t)(cv[i] * wv[i] * rnf * ZSCALE);
    *(f16x8*)&zb[(size_t)n * KK + tid * 8] = o8;
}

// ---------------------------------------------------------------------------
// K2: f16 MFMA GEMM out = Z Z^T / 16, fused mask + boundary worklist.
// 128x128 tile, BK=32, 4 waves, tri-grid (528 blocks = 2/CU co-resident).
// TRIPLE-buffered counted-vmcnt pipeline (depth 2 K-tiles):
//   STAGE(buf[(kt+2)%3], kt+2)[4 gload_lds] -> vmcnt(8) -> s_barrier
//   -> 8 ds_read_b128 + 16 MFMA -> lgkmcnt(0) -> s_barrier
// Loads get TWO full compute phases (~300+ cyc) to fly, covering L2/L3
// latency; vmcnt never 0 in the main loop.
// LDS: 48 KB stage + 8 KB worklist = 56 KB -> 2 blocks/CU.
// Swizzle sigma(row)=(row>>1)&3 on stage-source and read (conflict-free, r6).
// ---------------------------------------------------------------------------
template <bool FUSED>
__global__ __launch_bounds__(256, 4) void k_gemm(const half_t* __restrict__ zb,
                                                 float* __restrict__ out,
                                                 unsigned* __restrict__ gcnt,
                                                 unsigned* __restrict__ govf,
                                                 unsigned* __restrict__ glist) {
    __shared__ __align__(16) half_t As[3][128 * 32];
    __shared__ __align__(16) half_t Bs[3][128 * 32];
    __shared__ unsigned lds_list[LCAP];
    __shared__ unsigned lds_cnt, lds_base, lds_tot;

    int tid = threadIdx.x;
    if (FUSED && tid == 0) lds_cnt = 0;

    int lane = tid & 63, wv = tid >> 6;
    int wr = wv >> 1, wc = wv & 1;

    // XCD-chunked swizzle (528 = 8*66, bijective), then triangular decode
    int braw = blockIdx.x;
    int b = (braw & 7) * (NBLK / 8) + (braw >> 3);
    int ti = 0;
    while (b >= NT - ti) { b -= NT - ti; ++ti; }
    int tj = ti + b;
    int n0 = ti * 128, m0 = tj * 128;

    f32x4 acc[4][4] = {};
    int lrow = lane >> 2;                                  // staging row-in-slice
    int lchunk = (((lane & 3) ^ ((lrow >> 1) & 3)) * 8);   // swizzled source k-chunk

    auto STAGE = [&](int buf, int kt) {                    // 4 gload_lds per wave
        int k0 = kt * 32;
#pragma unroll
        for (int h = 0; h < 2; ++h) {
            int s = h * 4 + wv;
            int row = s * 16 + lrow;
            __builtin_amdgcn_global_load_lds(
                (gptr_t)(zb + (size_t)(n0 + row) * KK + k0 + lchunk),
                (lptr_t)(&As[buf][s * 512]), 16, 0, 0);
            __builtin_amdgcn_global_load_lds(
                (gptr_t)(zb + (size_t)(m0 + row) * KK + k0 + lchunk),
                (lptr_t)(&Bs[buf][s * 512]), 16, 0, 0);
        }
    };

    int kk_c = lane >> 4;
    int rsel = lane & 15;
    int kphys = (kk_c ^ ((rsel >> 1) & 3)) * 8;            // swizzled read offset

    auto COMPUTE = [&](int cur) {
        f16x8 af[4], bfr[4];
#pragma unroll
        for (int f = 0; f < 4; ++f) {
            af[f]  = *(f16x8*)&As[cur][(wr * 64 + f * 16 + rsel) * 32 + kphys];
            bfr[f] = *(f16x8*)&Bs[cur][(wc * 64 + f * 16 + rsel) * 32 + kphys];
        }
#pragma unroll
        for (int i = 0; i < 4; ++i)
#pragma unroll
            for (int j = 0; j < 4; ++j)
                acc[i][j] = __builtin_amdgcn_mfma_f32_16x16x32_f16(af[i], bfr[j], acc[i][j], 0, 0, 0);
    };

#define VMW(nn) asm volatile("s_waitcnt vmcnt(" #nn ")" ::: "memory");        \
                __builtin_amdgcn_sched_barrier(0);                            \
                __builtin_amdgcn_s_barrier();                                 \
                __builtin_amdgcn_sched_barrier(0);
#define LGW     asm volatile("s_waitcnt lgkmcnt(0)" ::: "memory");            \
                __builtin_amdgcn_sched_barrier(0);                            \
                __builtin_amdgcn_s_barrier();                                 \
                __builtin_amdgcn_sched_barrier(0);

    STAGE(0, 0);                       // prologue: two tiles in flight
    STAGE(1, 1);

#pragma unroll 3
    for (int kt = 0; kt < 62; ++kt) {
        STAGE((kt + 2) % 3, kt + 2);   // two tiles ahead (4 loads, stay in flight)
        VMW(8)                          // kt's 4 loads done; kt+1, kt+2 in flight
        COMPUTE(kt % 3);
        LGW
    }
    // peeled tail: kt = 62, 63 (nothing left to stage)
    VMW(4) COMPUTE(2); LGW
    VMW(0) COMPUTE(0);

#undef VMW
#undef LGW

    int colD = lane & 15, rq = lane >> 4;
    bool mir = (ti != tj);
#pragma unroll
    for (int i = 0; i < 4; ++i)
#pragma unroll
        for (int j = 0; j < 4; ++j) {
            int rbase = n0 + wr * 64 + i * 16 + rq * 4;
            int ccol = m0 + wc * 64 + j * 16 + colD;
            float4 mv;
#pragma unroll
            for (int q = 0; q < 4; ++q) {
                float a = acc[i][j][q] * OSCALE;
                float sv;
                if (FUSED) {
                    bool flg = fabsf(a - 0.1f) < WIN;
                    sv = flg ? a : (a > 0.1f ? a : 0.0f);
                    if (flg) {
                        unsigned pos = atomicAdd(&lds_cnt, 1u);
                        unsigned ent = (unsigned)(rbase + q) | ((unsigned)ccol << 12) |
                                       (mir ? (1u << 24) : 0u);
                        if (pos < LCAP) lds_list[pos] = ent;
                    }
                } else {
                    sv = a;
                }
                out[(size_t)(rbase + q) * N + ccol] = sv;
                ((float*)&mv)[q] = sv;
            }
            if (mir) *(float4*)&out[(size_t)ccol * N + rbase] = mv;
        }

    if (FUSED) {
        __syncthreads();
        if (tid == 0) {
            unsigned tot = lds_cnt;
            unsigned cnt = tot > LCAP ? LCAP : tot;
            lds_tot = cnt;
            lds_base = atomicAdd(gcnt, cnt);
            if (tot > LCAP) atomicOr(govf, 1u);
        }
        __syncthreads();
        unsigned cnt = lds_tot, base = lds_base;
        for (unsigned e = tid; e < cnt; e += 256) {
            unsigned gi = base + e;
            if (gi < CAP) glist[gi] = lds_list[e];
            else atomicOr(govf, 1u);
        }
    }
}

// ---------------------------------------------------------------------------
// K3: exact f64 recompute of worklist entries — one entry per lane, 16
// independent f64 accumulators, float4 gathers, LDS-broadcast w^2.
// ---------------------------------------------------------------------------
__global__ __launch_bounds__(256) void k_fix2(const float* __restrict__ c,
                                              const float* __restrict__ w,
                                              const double* __restrict__ rnorm,
                                              const unsigned* __restrict__ gcnt,
                                              const unsigned* __restrict__ glist,
                                              float* __restrict__ out) {
    __shared__ double w2[D * P];   // w2[d*16+p], 16 KB
    for (int e = threadIdx.x; e < P * D; e += 256) {
        int p = e >> 7, d = e & 127;
        double wv = (double)w[p * D + d];
        w2[d * P + p] = wv * wv;
    }
    __syncthreads();

    unsigned count = *gcnt;
    if (count > CAP) count = CAP;
    unsigned stride = gridDim.x * 256;
    for (unsigned e = blockIdx.x * 256 + threadIdx.x; e < count; e += stride) {
        unsigned u = glist[e];
        int n = u & 4095, m = (u >> 12) & 4095;
        const float* cn = c + (size_t)n * D;
        const float* cm = c + (size_t)m * D;
        double acc[P];
#pragma unroll
        for (int p = 0; p < P; ++p) acc[p] = 0.0;
        for (int d0 = 0; d0 < D; d0 += 4) {
            float4 a4 = *(const float4*)&cn[d0];
            float4 b4 = *(const float4*)&cm[d0];
            float av[4] = {a4.x, a4.y, a4.z, a4.w};
            float bv[4] = {b4.x, b4.y, b4.z, b4.w};
#pragma unroll
            for (int q = 0; q < 4; ++q) {
                double pr = (double)av[q] * (double)bv[q];
#pragma unroll
                for (int p = 0; p < P; ++p) acc[p] += pr * w2[(d0 + q) * P + p];
            }
        }
        double t = 0.0;
#pragma unroll
        for (int p = 0; p < P; ++p)
            t += acc[p] * (rnorm[p * N + n] * rnorm[p * N + m]);
        double fin = t * 0.0625;
        float res = (fin > 0.1) ? (float)fin : 0.0f;
        out[(size_t)n * N + m] = res;
        if (u >> 24) out[(size_t)m * N + n] = res;
    }
}

// ---------------------------------------------------------------------------
// K4: overflow guard — full-pass resolve, only if worklist overflowed.
// ---------------------------------------------------------------------------
__global__ __launch_bounds__(256) void k_guard(const float* __restrict__ c,
                                               const float* __restrict__ w,
                                               const double* __restrict__ rnorm,
                                               const unsigned* __restrict__ govf,
                                               float* __restrict__ out) {
    if (*govf == 0) return;
    __shared__ double w2[D * P];
    for (int e = threadIdx.x; e < P * D; e += 256) {
        int p = e >> 7, d = e & 127;
        double wv = (double)w[p * D + d];
        w2[d * P + p] = wv * wv;
    }
    __syncthreads();
    size_t stride = (size_t)gridDim.x * 256;
    for (size_t idx = (size_t)blockIdx.x * 256 + threadIdx.x; idx < (size_t)N * N;
         idx += stride) {
        float a = out[idx];
        if (fabsf(a - 0.1f) >= WIN) {
            out[idx] = (a > 0.1f) ? a : 0.0f;
            continue;
        }
        int n = (int)(idx >> 12), m = (int)(idx & (N - 1));
        const float* cn = c + (size_t)n * D;
        const float* cm = c + (size_t)m * D;
        double acc[P];
#pragma unroll
        for (int p = 0; p < P; ++p) acc[p] = 0.0;
        for (int d0 = 0; d0 < D; d0 += 4) {
            float4 a4 = *(const float4*)&cn[d0];
            float4 b4 = *(const float4*)&cm[d0];
            float av[4] = {a4.x, a4.y, a4.z, a4.w};
            float bv[4] = {b4.x, b4.y, b4.z, b4.w};
#pragma unroll
            for (int q = 0; q < 4; ++q) {
                double pr = (double)av[q] * (double)bv[q];
#pragma unroll
                for (int p = 0; p < P; ++p) acc[p] += pr * w2[(d0 + q) * P + p];
            }
        }
        double t = 0.0;
#pragma unroll
        for (int p = 0; p < P; ++p)
            t += acc[p] * (rnorm[p * N + n] * rnorm[p * N + m]);
        double fin = t * 0.0625;
        out[idx] = (fin > 0.1) ? (float)fin : 0.0f;
    }
}

// ---------------------------------------------------------------------------
// Fallback full-pass mask fix (only if ws too small; proven not taken).
// ---------------------------------------------------------------------------
__global__ __launch_bounds__(256) void k_fix_full(const float* __restrict__ c,
                                                  const float* __restrict__ w,
                                                  const double* __restrict__ rnorm,
                                                  float* __restrict__ out) {
    __shared__ double w2[D * P];
    for (int e = threadIdx.x; e < P * D; e += 256) {
        int p = e >> 7, d = e & 127;
        double wv = (double)w[p * D + d];
        w2[d * P + p] = wv * wv;
    }
    __syncthreads();
    size_t stride = (size_t)gridDim.x * 256;
    for (size_t idx = (size_t)blockIdx.x * 256 + threadIdx.x; idx < (size_t)N * N;
         idx += stride) {
        float a = out[idx];
        if (fabsf(a - 0.1f) >= WIN) {
            out[idx] = (a > 0.1f) ? a : 0.0f;
            continue;
        }
        int n = (int)(idx >> 12), m = (int)(idx & (N - 1));
        const float* cn = c + (size_t)n * D;
        const float* cm = c + (size_t)m * D;
        double acc[P];
#pragma unroll
        for (int p = 0; p < P; ++p) acc[p] = 0.0;
        for (int d0 = 0; d0 < D; d0 += 4) {
            float4 a4 = *(const float4*)&cn[d0];
            float4 b4 = *(const float4*)&cm[d0];
            float av[4] = {a4.x, a4.y, a4.z, a4.w};
            float bv[4] = {b4.x, b4.y, b4.z, b4.w};
#pragma unroll
            for (int q = 0; q < 4; ++q) {
                double pr = (double)av[q] * (double)bv[q];
#pragma unroll
                for (int p = 0; p < P; ++p) acc[p] += pr * w2[(d0 + q) * P + p];
            }
        }
        double t = 0.0;
#pragma unroll
        for (int p = 0; p < P; ++p)
            t += acc[p] * (rnorm[p * N + n] * rnorm[p * N + m]);
        double fin = t * 0.0625;
        out[idx] = (fin > 0.1) ? (float)fin : 0.0f;
    }
}

// ---------------------------------------------------------------------------
extern "C" void kernel_launch(void* const* d_in, const int* in_sizes, int n_in,
                              void* d_out, int out_size, void* d_ws, size_t ws_size,
                              hipStream_t stream) {
    const float* c = (const float*)d_in[0];
    const float* w = (const float*)d_in[1];
    float* out = (float*)d_out;
    char* ws = (char*)d_ws;

    double* rnorm = (double*)ws;                               // 512 KB
    size_t off = (size_t)P * N * 8;
    unsigned* gcnt = (unsigned*)(ws + off);
    unsigned* govf = gcnt + 1;
    unsigned* glist = (unsigned*)(ws + off + 128);             // 4 MB
    half_t* zb = (half_t*)(ws + off + 128 + (size_t)CAP * 4);  // 16 MB
    size_t need = off + 128 + (size_t)CAP * 4 + (size_t)N * KK * 2;

    if (ws_size >= need) {
        k_pack<<<N, 256, 0, stream>>>(c, w, rnorm, zb, gcnt, govf, 1);
        k_gemm<true><<<NBLK, 256, 0, stream>>>(zb, out, gcnt, govf, glist);
        k_fix2<<<1024, 256, 0, stream>>>(c, w, rnorm, gcnt, glist, out);
        k_guard<<<1024, 256, 0, stream>>>(c, w, rnorm, govf, out);
    } else {
        half_t* zb2 = (half_t*)(ws + off);
        k_pack<<<N, 256, 0, stream>>>(c, w, rnorm, zb2, nullptr, nullptr, 0);
        k_gemm<false><<<NBLK, 256, 0, stream>>>(zb2, out, nullptr, nullptr, nullptr);
        k_fix_full<<<4096, 256, 0, stream>>>(c, w, rnorm, out);
    }
}

// Round 11
// 111.155 us; speedup vs baseline: 1.0712x; 1.0712x over previous
//
#include <hip/hip_runtime.h>
#include <math.h>

#define N 4096
#define D 128
#define P 16
#define KK 2048                    // P*D
#define NTB 16                     // 256-wide tiles per dim
#define NBLK (NTB * NTB)           // full grid: 256 blocks = 1/CU (m201 config)
#define LCAPD 30000                // worklist capacity in aliased staging LDS
#define CAP (1u << 20)             // global worklist capacity (4 MB)
#define WIN 1.5e-3f                // > 1.1e-3 rigorous scaled-f16 bound
#define ZSCALE 256.0f              // 2^8, exact
#define OSCALE (1.0f / 16777216.0f * 16.0f)  // 2^-20, exact

typedef _Float16 half_t;
typedef __attribute__((ext_vector_type(8))) _Float16 f16x8;
typedef __attribute__((ext_vector_type(4))) float f32x4;
typedef __attribute__((address_space(1))) const unsigned int* gptr_t;
typedef __attribute__((address_space(3))) unsigned int* lptr_t;

#define MF(a, b, c) __builtin_amdgcn_mfma_f32_16x16x32_f16(a, b, c, 0, 0, 0)

// ---------------------------------------------------------------------------
// K1: fused norms (f64) + scaled f16 pack into TILED fragment-order layout.
// zb block (panel pn, k2 = global 32-k half index): 1024 pieces of 16B;
// piece(row r, chunk c) = r*4 + (c ^ ((r>>1)&3))  [swizzle pre-baked].
// ---------------------------------------------------------------------------
__global__ __launch_bounds__(256) void k_pack(const float* __restrict__ c,
                                              const float* __restrict__ w,
                                              double* __restrict__ rnorm,
                                              half_t* __restrict__ zb,
                                              unsigned* gcnt, unsigned* govf,
                                              int do_init) {
    int n = blockIdx.x, tid = threadIdx.x;
    if (do_init && n == 0 && tid == 0) { *gcnt = 0; *govf = 0; }
    int p = tid >> 4, d0 = (tid & 15) * 8;
    const float* cc = c + (size_t)n * D + d0;
    const float* ww = w + (size_t)p * D + d0;
    float cv[8], wv[8];
    *(float4*)&cv[0] = *(const float4*)&cc[0];
    *(float4*)&cv[4] = *(const float4*)&cc[4];
    *(float4*)&wv[0] = *(const float4*)&ww[0];
    *(float4*)&wv[4] = *(const float4*)&ww[4];
    double s = 0.0;
#pragma unroll
    for (int i = 0; i < 8; ++i) {
        double v = (double)cv[i] * (double)wv[i];
        s += v * v;
    }
#pragma unroll
    for (int o = 1; o < 16; o <<= 1) s += __shfl_xor(s, o, 64);
    double rn = 1.0 / fmax(sqrt(s), 1e-12);
    if ((tid & 15) == 0) rnorm[p * N + n] = rn;
    float rnf = (float)rn;
    f16x8 o8;
#pragma unroll
    for (int i = 0; i < 8; ++i) o8[i] = (half_t)(cv[i] * wv[i] * rnf * ZSCALE);

    int panel = n >> 8, rowin = n & 255;
    int k = p * 128 + d0;
    int k2 = k >> 5;                       // global k-half index (0..63)
    int cch = (k >> 3) & 3;                // logical chunk within half
    int piece = rowin * 4 + (cch ^ ((rowin >> 1) & 3));
    *(f16x8*)&zb[((size_t)(panel * 64 + k2) * 1024 + piece) * 8] = o8;
}

// ---------------------------------------------------------------------------
// K2: f16 MFMA GEMM out = Z Z^T / 16, fused mask + boundary worklist.
// 256x256 tile, BK=64 (2 k-halves), 8 waves (2M x 4N; wave tile 128x64),
// full grid (256 blocks = 1/CU). m201-style 4-phase/K-tile schedule:
//   p0: ds A-k0(8)+B-k0(4) | stage (A,k0)(t+1) | vmcnt(4) bar | 16 MFMA | bar
//   p1: ds B-k1(4)         | stage (B,k0)(t+1) | vmcnt(4) bar | 16 MFMA | bar
//   p2: ds A-k1(8)         | stage (B,k1)(t+1) | vmcnt(4) bar | 16 MFMA | bar
//   p3:                    | stage (A,k1)(t+1) | vmcnt(4) bar | 16 MFMA | bar
// Counted vmcnt(4) = 2 half-tiles in flight; stages only ever write buf^1
// (no intra-buffer WAR). Staging reads are contiguous 1KB/wave from the
// tiled zb; swizzle is pre-baked in zb (rule 21: both-sides-or-neither).
// LDS 128KB: 2 buf x [A-k0|B-k0|A-k1|B-k1] x 16KB.
// ---------------------------------------------------------------------------
template <bool FUSED>
__global__ __launch_bounds__(512, 2) void k_gemm(const half_t* __restrict__ zb,
                                                 float* __restrict__ out,
                                                 unsigned* __restrict__ gcnt,
                                                 unsigned* __restrict__ govf,
                                                 unsigned* __restrict__ glist) {
    __shared__ __align__(16) half_t smbuf[2][32768];   // 128 KB
    __shared__ unsigned wl3[4];

    int tid = threadIdx.x;
    int lane = tid & 63, wid = tid >> 6;
    int wm = wid >> 2, wn = wid & 3;                   // 2M x 4N waves

    int braw = blockIdx.x;                             // XCD swizzle (256 = 8x32)
    int b = (braw & 7) * 32 + (braw >> 3);
    int bi = b >> 4, bj = b & 15;
    int n0 = bi * 256, m0 = bj * 256;

    int rl = lane & 15, kc = lane >> 4;

    f32x4 acc[8][4] = {};

    // stage one 16KB half-tile: 2 x gload_lds(16B)/thread, contiguous source
    auto STAGEH = [&](int bsel, int seg, int pn, int k2) {
#pragma unroll
        for (int l = 0; l < 2; ++l) {
            const half_t* src = zb + ((size_t)(pn * 64 + k2) * 8192
                                      + (size_t)(wid * 128 + l * 64 + lane) * 8);
            __builtin_amdgcn_global_load_lds(
                (gptr_t)src,
                (lptr_t)(&smbuf[0][0] + bsel * 32768 + seg + (wid * 128 + l * 64) * 8),
                16, 0, 0);
        }
    };
    // frag read: rows R..R+15 of a half-tile, lane's k-chunk, swizzled
    auto LDF = [&](int bsel, int seg, int R) -> f16x8 {
        int r = R + rl;
        return *(const f16x8*)&smbuf[0][bsel * 32768 + seg +
                                       (r * 4 + (kc ^ ((r >> 1) & 3))) * 8];
    };

#define SYNC  __builtin_amdgcn_sched_barrier(0); __builtin_amdgcn_s_barrier(); \
              __builtin_amdgcn_sched_barrier(0);
#define VMC(nn) asm volatile("s_waitcnt vmcnt(" #nn ")" ::: "memory");

    // prologue: tile 0, age order matching steady state: A0, B0, B1, A1
    STAGEH(0, 0,     bi, 0);
    STAGEH(0, 8192,  bj, 0);
    STAGEH(0, 24576, bj, 1);
    STAGEH(0, 16384, bi, 1);
    VMC(4) SYNC                       // A0,B0 landed; B1,A1 in flight

    f16x8 af[8], bf0[4], bf1[4];

    for (int kt = 0; kt < 31; ++kt) {
        int bs = kt & 1, bn = bs ^ 1;
        int k2n = (kt + 1) * 2;
        // ---- phase 0: quad (k0, cols 0-31)
#pragma unroll
        for (int fi = 0; fi < 8; ++fi) af[fi] = LDF(bs, 0, wm * 128 + fi * 16);
#pragma unroll
        for (int j = 0; j < 4; ++j) bf0[j] = LDF(bs, 8192, wn * 64 + j * 16);
        STAGEH(bn, 0, bi, k2n);
        VMC(4) SYNC
        __builtin_amdgcn_s_setprio(1);
#pragma unroll
        for (int fi = 0; fi < 8; ++fi) {
            acc[fi][0] = MF(af[fi], bf0[0], acc[fi][0]);
            acc[fi][1] = MF(af[fi], bf0[1], acc[fi][1]);
        }
        __builtin_amdgcn_s_setprio(0);
        SYNC
        // ---- phase 1: quad (k0, cols 32-63)
#pragma unroll
        for (int j = 0; j < 4; ++j) bf1[j] = LDF(bs, 24576, wn * 64 + j * 16);
        STAGEH(bn, 8192, bj, k2n);
        VMC(4) SYNC
        __builtin_amdgcn_s_setprio(1);
#pragma unroll
        for (int fi = 0; fi < 8; ++fi) {
            acc[fi][2] = MF(af[fi], bf0[2], acc[fi][2]);
            acc[fi][3] = MF(af[fi], bf0[3], acc[fi][3]);
        }
        __builtin_amdgcn_s_setprio(0);
        SYNC
        // ---- phase 2: quad (k1, cols 0-31)
#pragma unroll
        for (int fi = 0; fi < 8; ++fi) af[fi] = LDF(bs, 16384, wm * 128 + fi * 16);
        STAGEH(bn, 24576, bj, k2n + 1);
        VMC(4) SYNC
        __builtin_amdgcn_s_setprio(1);
#pragma unroll
        for (int fi = 0; fi < 8; ++fi) {
            acc[fi][0] = MF(af[fi], bf1[0], acc[fi][0]);
            acc[fi][1] = MF(af[fi], bf1[1], acc[fi][1]);
        }
        __builtin_amdgcn_s_setprio(0);
        SYNC
        // ---- phase 3: quad (k1, cols 32-63)
        STAGEH(bn, 16384, bi, k2n + 1);
        VMC(4) SYNC
        __builtin_amdgcn_s_setprio(1);
#pragma unroll
        for (int fi = 0; fi < 8; ++fi) {
            acc[fi][2] = MF(af[fi], bf1[2], acc[fi][2]);
            acc[fi][3] = MF(af[fi], bf1[3], acc[fi][3]);
        }
        __builtin_amdgcn_s_setprio(0);
        SYNC
    }
    // ---- tail: kt = 31 (buf 1), nothing left to stage
    {
#pragma unroll
        for (int fi = 0; fi < 8; ++fi) af[fi] = LDF(1, 0, wm * 128 + fi * 16);
#pragma unroll
        for (int j = 0; j < 4; ++j) bf0[j] = LDF(1, 8192, wn * 64 + j * 16);
        VMC(2) SYNC
#pragma unroll
        for (int fi = 0; fi < 8; ++fi) {
            acc[fi][0] = MF(af[fi], bf0[0], acc[fi][0]);
            acc[fi][1] = MF(af[fi], bf0[1], acc[fi][1]);
        }
        SYNC
#pragma unroll
        for (int j = 0; j < 4; ++j) bf1[j] = LDF(1, 24576, wn * 64 + j * 16);
        VMC(0) SYNC
#pragma unroll
        for (int fi = 0; fi < 8; ++fi) {
            acc[fi][2] = MF(af[fi], bf0[2], acc[fi][2]);
            acc[fi][3] = MF(af[fi], bf0[3], acc[fi][3]);
        }
        SYNC
#pragma unroll
        for (int fi = 0; fi < 8; ++fi) af[fi] = LDF(1, 16384, wm * 128 + fi * 16);
#pragma unroll
        for (int fi = 0; fi < 8; ++fi) {
            acc[fi][0] = MF(af[fi], bf1[0], acc[fi][0]);
            acc[fi][1] = MF(af[fi], bf1[1], acc[fi][1]);
        }
#pragma unroll
        for (int fi = 0; fi < 8; ++fi) {
            acc[fi][2] = MF(af[fi], bf1[2], acc[fi][2]);
            acc[fi][3] = MF(af[fi], bf1[3], acc[fi][3]);
        }
    }
#undef SYNC
#undef VMC

    // staging LDS dead -> alias as worklist
    unsigned* lds_list = (unsigned*)&smbuf[0][0];
    __syncthreads();
    if (FUSED) {
        if (tid == 0) wl3[0] = 0;
        __syncthreads();
    }

#pragma unroll
    for (int fi = 0; fi < 8; ++fi)
#pragma unroll
        for (int fj = 0; fj < 4; ++fj) {
            int rbase = n0 + wm * 128 + fi * 16 + kc * 4;
            int ccol = m0 + wn * 64 + fj * 16 + rl;
#pragma unroll
            for (int q = 0; q < 4; ++q) {
                float a = acc[fi][fj][q] * OSCALE;
                float sv;
                if (FUSED) {
                    bool flg = fabsf(a - 0.1f) < WIN;
                    sv = flg ? a : (a > 0.1f ? a : 0.0f);
                    if (flg) {
                        unsigned pos = atomicAdd(&wl3[0], 1u);
                        if (pos < LCAPD)
                            lds_list[pos] = (unsigned)(rbase + q) | ((unsigned)ccol << 12);
                    }
                } else {
                    sv = a;
                }
                out[(size_t)(rbase + q) * N + ccol] = sv;
            }
        }

    if (FUSED) {
        __syncthreads();
        if (tid == 0) {
            unsigned tot = wl3[0];
            unsigned cnt = tot > LCAPD ? LCAPD : tot;
            wl3[2] = cnt;
            wl3[1] = atomicAdd(gcnt, cnt);
            if (tot > LCAPD) atomicOr(govf, 1u);
        }
        __syncthreads();
        unsigned cnt = wl3[2], base = wl3[1];
        for (unsigned e = tid; e < cnt; e += 512) {
            unsigned gi = base + e;
            if (gi < CAP) glist[gi] = lds_list[e];
            else atomicOr(govf, 1u);
        }
    }
}

// ---------------------------------------------------------------------------
// K3: exact f64 recompute of worklist entries — one entry per lane.
// ---------------------------------------------------------------------------
__global__ __launch_bounds__(256) void k_fix2(const float* __restrict__ c,
                                              const float* __restrict__ w,
                                              const double* __restrict__ rnorm,
                                              const unsigned* __restrict__ gcnt,
                                              const unsigned* __restrict__ glist,
                                              float* __restrict__ out) {
    __shared__ double w2[D * P];
    for (int e = threadIdx.x; e < P * D; e += 256) {
        int p = e >> 7, d = e & 127;
        double wv = (double)w[p * D + d];
        w2[d * P + p] = wv * wv;
    }
    __syncthreads();

    unsigned count = *gcnt;
    if (count > CAP) count = CAP;
    unsigned stride = gridDim.x * 256;
    for (unsigned e = blockIdx.x * 256 + threadIdx.x; e < count; e += stride) {
        unsigned u = glist[e];
        int n = u & 4095, m = (u >> 12) & 4095;
        const float* cn = c + (size_t)n * D;
        const float* cm = c + (size_t)m * D;
        double acc[P];
#pragma unroll
        for (int p = 0; p < P; ++p) acc[p] = 0.0;
        for (int d0 = 0; d0 < D; d0 += 4) {
            float4 a4 = *(const float4*)&cn[d0];
            float4 b4 = *(const float4*)&cm[d0];
            float av[4] = {a4.x, a4.y, a4.z, a4.w};
            float bv[4] = {b4.x, b4.y, b4.z, b4.w};
#pragma unroll
            for (int q = 0; q < 4; ++q) {
                double pr = (double)av[q] * (double)bv[q];
#pragma unroll
                for (int p = 0; p < P; ++p) acc[p] += pr * w2[(d0 + q) * P + p];
            }
        }
        double t = 0.0;
#pragma unroll
        for (int p = 0; p < P; ++p)
            t += acc[p] * (rnorm[p * N + n] * rnorm[p * N + m]);
        double fin = t * 0.0625;
        out[(size_t)n * N + m] = (fin > 0.1) ? (float)fin : 0.0f;
    }
}

// ---------------------------------------------------------------------------
// K4: overflow guard — full-pass resolve, only if worklist overflowed.
// ---------------------------------------------------------------------------
__global__ __launch_bounds__(256) void k_guard(const float* __restrict__ c,
                                               const float* __restrict__ w,
                                               const double* __restrict__ rnorm,
                                               const unsigned* __restrict__ govf,
                                               float* __restrict__ out) {
    if (*govf == 0) return;
    __shared__ double w2[D * P];
    for (int e = threadIdx.x; e < P * D; e += 256) {
        int p = e >> 7, d = e & 127;
        double wv = (double)w[p * D + d];
        w2[d * P + p] = wv * wv;
    }
    __syncthreads();
    size_t stride = (size_t)gridDim.x * 256;
    for (size_t idx = (size_t)blockIdx.x * 256 + threadIdx.x; idx < (size_t)N * N;
         idx += stride) {
        float a = out[idx];
        if (fabsf(a - 0.1f) >= WIN) {
            out[idx] = (a > 0.1f) ? a : 0.0f;
            continue;
        }
        int n = (int)(idx >> 12), m = (int)(idx & (N - 1));
        const float* cn = c + (size_t)n * D;
        const float* cm = c + (size_t)m * D;
        double acc[P];
#pragma unroll
        for (int p = 0; p < P; ++p) acc[p] = 0.0;
        for (int d0 = 0; d0 < D; d0 += 4) {
            float4 a4 = *(const float4*)&cn[d0];
            float4 b4 = *(const float4*)&cm[d0];
            float av[4] = {a4.x, a4.y, a4.z, a4.w};
            float bv[4] = {b4.x, b4.y, b4.z, b4.w};
#pragma unroll
            for (int q = 0; q < 4; ++q) {
                double pr = (double)av[q] * (double)bv[q];
#pragma unroll
                for (int p = 0; p < P; ++p) acc[p] += pr * w2[(d0 + q) * P + p];
            }
        }
        double t = 0.0;
#pragma unroll
        for (int p = 0; p < P; ++p)
            t += acc[p] * (rnorm[p * N + n] * rnorm[p * N + m]);
        double fin = t * 0.0625;
        out[idx] = (fin > 0.1) ? (float)fin : 0.0f;
    }
}

// ---------------------------------------------------------------------------
// Fallback full-pass mask fix (only if ws too small; proven not taken).
// ---------------------------------------------------------------------------
__global__ __launch_bounds__(256) void k_fix_full(const float* __restrict__ c,
                                                  const float* __restrict__ w,
                                                  const double* __restrict__ rnorm,
                                                  float* __restrict__ out) {
    __shared__ double w2[D * P];
    for (int e = threadIdx.x; e < P * D; e += 256) {
        int p = e >> 7, d = e & 127;
        double wv = (double)w[p * D + d];
        w2[d * P + p] = wv * wv;
    }
    __syncthreads();
    size_t stride = (size_t)gridDim.x * 256;
    for (size_t idx = (size_t)blockIdx.x * 256 + threadIdx.x; idx < (size_t)N * N;
         idx += stride) {
        float a = out[idx];
        if (fabsf(a - 0.1f) >= WIN) {
            out[idx] = (a > 0.1f) ? a : 0.0f;
            continue;
        }
        int n = (int)(idx >> 12), m = (int)(idx & (N - 1));
        const float* cn = c + (size_t)n * D;
        const float* cm = c + (size_t)m * D;
        double acc[P];
#pragma unroll
        for (int p = 0; p < P; ++p) acc[p] = 0.0;
        for (int d0 = 0; d0 < D; d0 += 4) {
            float4 a4 = *(const float4*)&cn[d0];
            float4 b4 = *(const float4*)&cm[d0];
            float av[4] = {a4.x, a4.y, a4.z, a4.w};
            float bv[4] = {b4.x, b4.y, b4.z, b4.w};
#pragma unroll
            for (int q = 0; q < 4; ++q) {
                double pr = (double)av[q] * (double)bv[q];
#pragma unroll
                for (int p = 0; p < P; ++p) acc[p] += pr * w2[(d0 + q) * P + p];
            }
        }
        double t = 0.0;
#pragma unroll
        for (int p = 0; p < P; ++p)
            t += acc[p] * (rnorm[p * N + n] * rnorm[p * N + m]);
        double fin = t * 0.0625;
        out[idx] = (fin > 0.1) ? (float)fin : 0.0f;
    }
}

// ---------------------------------------------------------------------------
extern "C" void kernel_launch(void* const* d_in, const int* in_sizes, int n_in,
                              void* d_out, int out_size, void* d_ws, size_t ws_size,
                              hipStream_t stream) {
    const float* c = (const float*)d_in[0];
    const float* w = (const float*)d_in[1];
    float* out = (float*)d_out;
    char* ws = (char*)d_ws;

    double* rnorm = (double*)ws;                               // 512 KB
    size_t off = (size_t)P * N * 8;
    unsigned* gcnt = (unsigned*)(ws + off);
    unsigned* govf = gcnt + 1;
    unsigned* glist = (unsigned*)(ws + off + 128);             // 4 MB
    half_t* zb = (half_t*)(ws + off + 128 + (size_t)CAP * 4);  // 16 MB tiled
    size_t need = off + 128 + (size_t)CAP * 4 + (size_t)N * KK * 2;

    if (ws_size >= need) {
        k_pack<<<N, 256, 0, stream>>>(c, w, rnorm, zb, gcnt, govf, 1);
        k_gemm<true><<<NBLK, 512, 0, stream>>>(zb, out, gcnt, govf, glist);
        k_fix2<<<1024, 256, 0, stream>>>(c, w, rnorm, gcnt, glist, out);
        k_guard<<<1024, 256, 0, stream>>>(c, w, rnorm, govf, out);
    } else {
        half_t* zb2 = (half_t*)(ws + off);
        k_pack<<<N, 256, 0, stream>>>(c, w, rnorm, zb2, nullptr, nullptr, 0);
        k_gemm<false><<<NBLK, 512, 0, stream>>>(zb2, out, nullptr, nullptr, nullptr);
        k_fix_full<<<4096, 256, 0, stream>>>(c, w, rnorm, out);
    }
}